// Round 4
// baseline (222.378 us; speedup 1.0000x reference)
//
#include <hip/hip_runtime.h>
#include <hip/hip_bf16.h>
#include <hip/hip_cooperative_groups.h>
#include <math.h>

namespace cg = cooperative_groups;

// out[b,f,t] = sum_l sig[b,l] * win[t,l] * cos(2*pi*fv[f]*l/8192)
// Split-K f16 MFMA GEMM: D[t][f] = win[t][:] . (ctab*sig)[f][:]^T per b.
// B=32, L=8192, F=T=128.  fv/tc = linspace->int32 reproduced exactly (R0).
// R4: single cooperative kernel (tables -> grid.sync -> gemm -> grid.sync ->
// reduce) to kill launch gaps and get per-phase counter visibility.

#define L_ 8192
#define B_ 32
#define SPLITK 16
#define KCHUNK 512   // L_/SPLITK
#define BK 64
#define STEPS 8      // KCHUNK/BK

typedef _Float16 half8 __attribute__((ext_vector_type(8)));
typedef float float4v __attribute__((ext_vector_type(4)));

// ws layout:
// [0,2MB)    win_blk [128 kblk][128 t][8 chunks(^t&7)][8 f16]
// [2MB,4MB)  ctab    [128 f][8192] f16
// [4MB,4.5M) sig_f16 [32][8192]
// [4.5M,36.5M) partial [16][32][128 f][128 t] fp32
#define WS_WIN 0
#define WS_CTAB (2u * 1024u * 1024u)
#define WS_SIG (4u * 1024u * 1024u)
#define WS_PART (4u * 1024u * 1024u + 512u * 1024u)

#define GLD_LDS16(gsrc, ldst)                                              \
  __builtin_amdgcn_global_load_lds(                                        \
      (const __attribute__((address_space(1))) void*)(gsrc),               \
      (__attribute__((address_space(3))) void*)(ldst), 16, 0, 0)

struct SmemT {
  _Float16 As[2][128 * 64];  // 16 KB each, swizzled rows of 64
  _Float16 Bs[2][128][72];   // 18 KB each, +8 pad
};

__device__ __forceinline__ void phase_tables(int bx, int tid,
                                             const float* __restrict__ signal,
                                             char* __restrict__ ws) {
  _Float16* win_blk = (_Float16*)(ws + WS_WIN);
  _Float16* ctab = (_Float16*)(ws + WS_CTAB);
  _Float16* sigh = (_Float16*)(ws + WS_SIG);
  if (bx < 128) {  // gaussian window row t -> blocked + swizzled
    const int t = bx;
    const float tc = truncf((float)t * (8191.0f / 127.0f));
    const float inv_sw = 1.0f / 819.2f;
    for (int l = tid; l < L_; l += 256) {
      float d = ((float)l - tc) * inv_sw;
      int kblk = l >> 6, c = (l >> 3) & 7, e = l & 7;
      win_blk[(((kblk << 7) + t) << 6) + (((c ^ (t & 7)) << 3) + e)] =
          (_Float16)__expf(-0.5f * d * d);
    }
  } else if (bx < 256) {  // cos row f, exact integer phase mod 8192
    const int f = bx - 128;
    const int fv = (int)((float)f * (4096.0f / 127.0f));
    const float cstep = (float)(2.0 * M_PI / 8192.0);
    for (int l = tid; l < L_; l += 256) {
      int m = (fv * l) & (L_ - 1);
      ctab[(size_t)f * L_ + l] = (_Float16)__cosf((float)m * cstep);
    }
  } else if (bx < 256 + B_) {  // signal -> f16
    const int b = bx - 256;
    for (int l = tid; l < L_; l += 256)
      sigh[b * L_ + l] = (_Float16)signal[b * L_ + l];
  }
}

__device__ __forceinline__ void phase_gemm(int bx, int tid,
                                           char* __restrict__ ws, SmemT& sm) {
  const _Float16* win_blk = (const _Float16*)(ws + WS_WIN);
  const _Float16* ctab = (const _Float16*)(ws + WS_CTAB);
  const _Float16* sigh = (const _Float16*)(ws + WS_SIG);
  float* partial = (float*)(ws + WS_PART);

  const int kc = bx & (SPLITK - 1);
  const int b = bx >> 4;

  const int lane = tid & 63;
  const int wv = tid >> 6;
  const int wm = (wv >> 1) * 64;  // t quadrant
  const int wn = (wv & 1) * 64;   // f quadrant
  const int frow = lane & 15;
  const int quad = lane >> 4;

  const int r0 = tid >> 3;       // 0..31 (Bs staging row base)
  const int c8 = (tid & 7) * 8;  // 0..56

  float4v acc[4][4];
#pragma unroll
  for (int i = 0; i < 4; ++i)
#pragma unroll
    for (int j = 0; j < 4; ++j) acc[i][j] = (float4v)(0.0f);

  half8 cv[4], sv;

#define STAGE_A(s, buf)                                                     \
  {                                                                         \
    const _Float16* asrc = win_blk + (((size_t)(kc * STEPS + (s)) << 13));  \
    _Float16* adst = &sm.As[buf][0];                                        \
    GLD_LDS16(asrc + tid * 8, adst + tid * 8);                              \
    GLD_LDS16(asrc + 2048 + tid * 8, adst + 2048 + tid * 8);                \
    GLD_LDS16(asrc + 4096 + tid * 8, adst + 4096 + tid * 8);                \
    GLD_LDS16(asrc + 6144 + tid * 8, adst + 6144 + tid * 8);                \
  }
#define LOAD_B(s)                                                           \
  {                                                                         \
    const int l0 = kc * KCHUNK + (s)*BK;                                    \
    sv = *(const half8*)(sigh + (size_t)b * L_ + l0 + c8);                  \
    _Pragma("unroll") for (int rep = 0; rep < 4; ++rep) cv[rep] =           \
        *(const half8*)(ctab + (size_t)(r0 + rep * 32) * L_ + l0 + c8);     \
  }
#define WRITE_B(buf)                                                        \
  {                                                                         \
    _Pragma("unroll") for (int rep = 0; rep < 4; ++rep)                     \
        *(half8*)&sm.Bs[buf][r0 + rep * 32][c8] = cv[rep] * sv;             \
  }

  STAGE_A(0, 0);
  LOAD_B(0);
  WRITE_B(0);

  for (int s = 0; s < STEPS; ++s) {
    const int cb = s & 1, nb = cb ^ 1;
    __syncthreads();  // buf cb ready (drains DMA + Bs writes)
    if (s + 1 < STEPS) {
      STAGE_A(s + 1, nb);
      LOAD_B(s + 1);
    }
#pragma unroll
    for (int kh = 0; kh < 2; ++kh) {
      half8 af[4], bf[4];
      const int chunk = kh * 4 + quad;
#pragma unroll
      for (int i = 0; i < 4; ++i) {
        const int r = wm + i * 16 + frow;
        af[i] = *(const half8*)&sm.As[cb][(r << 6) + ((chunk ^ (r & 7)) << 3)];
      }
#pragma unroll
      for (int j = 0; j < 4; ++j)
        bf[j] = *(const half8*)&sm.Bs[cb][wn + j * 16 + frow][kh * 32 + quad * 8];
#pragma unroll
      for (int i = 0; i < 4; ++i)
#pragma unroll
        for (int j = 0; j < 4; ++j)
          acc[i][j] = __builtin_amdgcn_mfma_f32_16x16x32_f16(af[i], bf[j],
                                                             acc[i][j], 0, 0, 0);
    }
    if (s + 1 < STEPS) WRITE_B(nb);
  }

  // partial[kc][b][f][t]; D frag: col(f)=lane&15, row(t)=(lane>>4)*4+reg
  float* pbase = partial + ((size_t)(kc * B_ + b) << 14);
  const int tq = quad * 4;
#pragma unroll
  for (int i = 0; i < 4; ++i) {
    const int t = wm + i * 16 + tq;
#pragma unroll
    for (int j = 0; j < 4; ++j) {
      const int f = wn + j * 16 + frow;
      *(float4v*)(pbase + f * 128 + t) = acc[i][j];
    }
  }
}

__device__ __forceinline__ void phase_reduce(int bx, int tid,
                                             const char* __restrict__ ws,
                                             float* __restrict__ out) {
  const float* partial = (const float*)(ws + WS_PART);
  const size_t gi = ((size_t)bx * 256 + tid) * 4;  // < 524288
  float4v s = (float4v)(0.0f);
#pragma unroll
  for (int kc = 0; kc < SPLITK; ++kc)
    s += *(const float4v*)(partial + (size_t)kc * 524288 + gi);
  *(float4v*)(out + gi) = s;
}

__global__ __launch_bounds__(256, 2) void gabor_fused_kernel(
    const float* __restrict__ signal, float* __restrict__ out,
    char* __restrict__ ws) {
  __shared__ SmemT sm;
  cg::grid_group grid = cg::this_grid();
  phase_tables(blockIdx.x, threadIdx.x, signal, ws);
  grid.sync();
  phase_gemm(blockIdx.x, threadIdx.x, ws, sm);
  grid.sync();
  phase_reduce(blockIdx.x, threadIdx.x, ws, out);
}

// ---- standalone fallback kernels (if cooperative launch unavailable) ----
__global__ __launch_bounds__(256) void gabor_tables_kernel(
    const float* __restrict__ signal, char* __restrict__ ws) {
  phase_tables(blockIdx.x, threadIdx.x, signal, ws);
}
__global__ __launch_bounds__(256, 2) void gabor_gemm_kernel(char* __restrict__ ws) {
  __shared__ SmemT sm;
  phase_gemm(blockIdx.x, threadIdx.x, ws, sm);
}
__global__ __launch_bounds__(256) void gabor_reduce_kernel(
    const char* __restrict__ ws, float* __restrict__ out) {
  phase_reduce(blockIdx.x, threadIdx.x, ws, out);
}

extern "C" void kernel_launch(void* const* d_in, const int* in_sizes, int n_in,
                              void* d_out, int out_size, void* d_ws, size_t ws_size,
                              hipStream_t stream) {
  const float* signal = (const float*)d_in[0];
  float* out = (float*)d_out;
  char* ws = (char*)d_ws;
  void* args[] = {(void*)&signal, (void*)&out, (void*)&ws};
  hipError_t err = hipLaunchCooperativeKernel((void*)gabor_fused_kernel,
                                              dim3(B_ * SPLITK), dim3(256),
                                              args, 0, stream);
  if (err != hipSuccess) {
    gabor_tables_kernel<<<dim3(288), dim3(256), 0, stream>>>(signal, ws);
    gabor_gemm_kernel<<<dim3(B_ * SPLITK), dim3(256), 0, stream>>>(ws);
    gabor_reduce_kernel<<<dim3(512), dim3(256), 0, stream>>>(ws, out);
  }
}

// Round 5
// 94.507 us; speedup vs baseline: 2.3530x; 2.3530x over previous
//
#include <hip/hip_runtime.h>
#include <hip/hip_bf16.h>
#include <math.h>

// out[b,f,t] = sum_l sig[b,l] * win[t,l] * cos(2*pi*fv[f]*l/8192)
// Split-K f16 MFMA GEMM: D[t][f] = win[t][:] . (cos*sig)[f][:]^T per b.
// B=32, L=8192, F=T=128.  fv/tc = linspace->int32 reproduced exactly (R0).
// R5: NO table kernel, NO global staging, NO cooperative sync. Each block
// computes win/cos tiles inline (trans-pipe, ~quarter-rate VALU) straight
// into LDS each K-step. Tables are cheaper to recompute than to load.

#define L_ 8192
#define B_ 32
#define SPLITK 16
#define KCHUNK 512   // L_/SPLITK
#define BK 64
#define STEPS 8      // KCHUNK/BK

typedef _Float16 half8 __attribute__((ext_vector_type(8)));
typedef float float4v __attribute__((ext_vector_type(4)));

// ws layout: [0,32MB) partial [16 kc][32 b][128 f][128 t] fp32

__global__ __launch_bounds__(256, 2) void gabor_gemm_kernel(
    const float* __restrict__ signal, float* __restrict__ partial) {
  const int kc = blockIdx.x & (SPLITK - 1);
  const int b = blockIdx.x >> 4;
  const int tid = threadIdx.x;

  __shared__ _Float16 As[2][128 * 64];  // win rows(t), XOR-swizzled chunks
  __shared__ _Float16 Bs[2][128][72];   // (cos*sig) rows(f), +8 pad

  const int lane = tid & 63;
  const int wv = tid >> 6;
  const int wm = (wv >> 1) * 64;  // t quadrant
  const int wn = (wv & 1) * 64;   // f quadrant
  const int frow = lane & 15;
  const int quad = lane >> 4;

  const int r0 = tid >> 3;       // staging row base 0..31
  const int c8 = (tid & 7) * 8;  // col base 0..56
  const int cidx = tid & 7;      // chunk index

  const float tstep = 8191.0f / 127.0f;
  const float fstep = 4096.0f / 127.0f;
  const float inv_sw = 1.0f / 819.2f;
  const float cstep = (float)(2.0 * M_PI / 8192.0);

  // per-thread row constants (R0-verified linspace->int32 reproduction)
  float tc[4];
  int fv[4];
#pragma unroll
  for (int rep = 0; rep < 4; ++rep) {
    const int row = r0 + rep * 32;
    tc[rep] = truncf((float)row * tstep);
    fv[rep] = (int)((float)row * fstep);
  }

  float4v acc[4][4];
#pragma unroll
  for (int i = 0; i < 4; ++i)
#pragma unroll
    for (int j = 0; j < 4; ++j) acc[i][j] = (float4v)(0.0f);

  const float* srow = signal + (size_t)b * L_;

  // Compute win + cos*sig tiles for K-step s into buffer buf.
#define STAGE(s, buf)                                                        \
  {                                                                          \
    const int l0 = kc * KCHUNK + (s)*BK;                                     \
    float sg[8];                                                             \
    *(float4v*)&sg[0] = *(const float4v*)(srow + l0 + c8);                   \
    *(float4v*)&sg[4] = *(const float4v*)(srow + l0 + c8 + 4);               \
    _Pragma("unroll") for (int rep = 0; rep < 4; ++rep) {                    \
      const int row = r0 + rep * 32;                                         \
      const float lbase = (float)(l0 + c8) - tc[rep];                        \
      half8 hw, hb;                                                          \
      _Pragma("unroll") for (int e = 0; e < 8; ++e) {                        \
        const float d = (lbase + (float)e) * inv_sw;                         \
        hw[e] = (_Float16)__expf(-0.5f * d * d);                             \
        const int m = __mul24(fv[rep], l0 + c8 + e) & (L_ - 1);              \
        hb[e] = (_Float16)(__cosf((float)m * cstep) * sg[e]);                \
      }                                                                      \
      *(half8*)&As[buf][(row << 6) + ((cidx ^ (row & 7)) << 3)] = hw;        \
      *(half8*)&Bs[buf][row][c8] = hb;                                       \
    }                                                                        \
  }

  STAGE(0, 0);

  for (int s = 0; s < STEPS; ++s) {
    const int cb = s & 1, nb = cb ^ 1;
    __syncthreads();  // buf cb tiles complete (LDS writes only - fast)
#pragma unroll
    for (int kh = 0; kh < 2; ++kh) {
      half8 af[4], bf[4];
      const int chunk = kh * 4 + quad;
#pragma unroll
      for (int i = 0; i < 4; ++i) {
        const int r = wm + i * 16 + frow;
        af[i] = *(const half8*)&As[cb][(r << 6) + ((chunk ^ (r & 7)) << 3)];
      }
#pragma unroll
      for (int j = 0; j < 4; ++j)
        bf[j] = *(const half8*)&Bs[cb][wn + j * 16 + frow][kh * 32 + quad * 8];
#pragma unroll
      for (int i = 0; i < 4; ++i)
#pragma unroll
        for (int j = 0; j < 4; ++j)
          acc[i][j] = __builtin_amdgcn_mfma_f32_16x16x32_f16(af[i], bf[j],
                                                             acc[i][j], 0, 0, 0);
    }
    if (s + 1 < STEPS) STAGE(s + 1, nb);  // overlaps MFMA via scheduler
  }

  // partial[kc][b][f][t]; D frag: col(f)=lane&15, row(t)=(lane>>4)*4+reg
  float* pbase = partial + ((size_t)(kc * B_ + b) << 14);
  const int tq = quad * 4;
#pragma unroll
  for (int i = 0; i < 4; ++i) {
    const int t = wm + i * 16 + tq;
#pragma unroll
    for (int j = 0; j < 4; ++j) {
      const int f = wn + j * 16 + frow;
      *(float4v*)(pbase + f * 128 + t) = acc[i][j];
    }
  }
}

__global__ __launch_bounds__(256) void gabor_reduce_kernel(
    const float* __restrict__ partial, float* __restrict__ out) {
  const size_t gi = ((size_t)blockIdx.x * 256 + threadIdx.x) * 4;  // < 524288
  float4v s = (float4v)(0.0f);
#pragma unroll
  for (int kc = 0; kc < SPLITK; ++kc)
    s += *(const float4v*)(partial + (size_t)kc * 524288 + gi);
  *(float4v*)(out + gi) = s;
}

extern "C" void kernel_launch(void* const* d_in, const int* in_sizes, int n_in,
                              void* d_out, int out_size, void* d_ws, size_t ws_size,
                              hipStream_t stream) {
  const float* signal = (const float*)d_in[0];
  float* out = (float*)d_out;
  float* partial = (float*)d_ws;
  gabor_gemm_kernel<<<dim3(B_ * SPLITK), dim3(256), 0, stream>>>(signal, partial);
  gabor_reduce_kernel<<<dim3(512), dim3(256), 0, stream>>>(partial, out);
}

// Round 6
// 86.379 us; speedup vs baseline: 2.5745x; 1.0941x over previous
//
#include <hip/hip_runtime.h>
#include <hip/hip_bf16.h>
#include <math.h>

// out[b,f,t] = sum_l sig[b,l] * win[t,l] * cos(2*pi*fv[f]*l/8192)
// Split-K f16 MFMA GEMM. R6: amortize table compute across b — each block
// handles 4 b's for one (kc, 64t, 64f) tile; win/cos tiles staged once per
// K-step, sig folded into the A-fragment in registers (pk_mul). Table VALU
// per MFMA drops 4x vs R5; MFMA becomes the critical pipe.
// fv/tc = linspace->int32 reproduced exactly in fp32 (R0-verified).

#define L_ 8192
#define B_ 32
#define SPLITK 16
#define KCHUNK 512   // L_/SPLITK
#define BK 64
#define STEPS 8      // KCHUNK/BK

typedef _Float16 half8 __attribute__((ext_vector_type(8)));
typedef float float4v __attribute__((ext_vector_type(4)));

// ws: [0,32MB) partial [16 kc][32 b][128 f][128 t] fp32

__global__ __launch_bounds__(256, 2) void gabor_gemm_kernel(
    const float* __restrict__ signal, float* __restrict__ partial) {
  const int bx = blockIdx.x;          // 512 blocks
  const int fhalf = bx & 1;
  const int thalf = (bx >> 1) & 1;
  const int bgrp = (bx >> 2) & 7;     // group of 4 b's
  const int kc = bx >> 5;             // 0..15
  const int tid = threadIdx.x;

  __shared__ _Float16 As[2][64 * 64];   // win rows(t), XOR-swizzled, 8 KB ea
  __shared__ _Float16 Bs[2][64][72];    // cos rows(f), +8 pad, 9 KB ea
  __shared__ _Float16 Sg[2][4][64];     // sig f16 per b, 512 B ea

  const int lane = tid & 63;
  const int wv = tid >> 6;
  const int wmt = (wv >> 1) * 32;  // t quadrant (32)
  const int wnf = (wv & 1) * 32;   // f quadrant (32)
  const int frow = lane & 15;
  const int quad = lane >> 4;

  const int r0 = tid >> 3;       // staging row 0..31 (+32 for rep 1)
  const int c8 = (tid & 7) * 8;  // col base 0..56
  const int cidx = tid & 7;      // chunk index for As swizzle

  const float tstep = 8191.0f / 127.0f;
  const float fstep = 4096.0f / 127.0f;
  const float inv_sw = 1.0f / 819.2f;
  const float cstep = (float)(2.0 * M_PI / 8192.0);

  float tc[2];
  int fv[2];
#pragma unroll
  for (int rep = 0; rep < 2; ++rep) {
    const int row = r0 + rep * 32;
    tc[rep] = truncf((float)(thalf * 64 + row) * tstep);
    fv[rep] = (int)((float)(fhalf * 64 + row) * fstep);
  }

  float4v acc[4][2][2];
#pragma unroll
  for (int bi = 0; bi < 4; ++bi)
#pragma unroll
    for (int i = 0; i < 2; ++i)
#pragma unroll
      for (int j = 0; j < 2; ++j) acc[bi][i][j] = (float4v)(0.0f);

  const float* sigbase = signal + (size_t)(bgrp * 4) * L_;

  // Stage win[64][64], cos[64][64], sig[4][64] for K-step s into buffer buf.
#define STAGE(s, buf)                                                        \
  {                                                                          \
    const int l0 = kc * KCHUNK + (s)*BK;                                     \
    Sg[buf][wv][lane] = (_Float16)sigbase[(size_t)wv * L_ + l0 + lane];      \
    _Pragma("unroll") for (int rep = 0; rep < 2; ++rep) {                    \
      const int row = r0 + rep * 32;                                         \
      const float lbase = (float)(l0 + c8) - tc[rep];                        \
      half8 hw, hb;                                                          \
      _Pragma("unroll") for (int e = 0; e < 8; ++e) {                        \
        const float d = (lbase + (float)e) * inv_sw;                         \
        hw[e] = (_Float16)__expf(-0.5f * d * d);                             \
        const int m = __mul24(fv[rep], l0 + c8 + e) & (L_ - 1);              \
        hb[e] = (_Float16)__cosf((float)m * cstep);                          \
      }                                                                      \
      *(half8*)&As[buf][(row << 6) + ((cidx ^ (row & 7)) << 3)] = hw;        \
      *(half8*)&Bs[buf][row][c8] = hb;                                       \
    }                                                                        \
  }

  STAGE(0, 0);

  for (int s = 0; s < STEPS; ++s) {
    const int cb = s & 1, nb = cb ^ 1;
    __syncthreads();  // buf cb complete
#pragma unroll
    for (int kh = 0; kh < 2; ++kh) {
      const int kk = kh * 32 + quad * 8;   // k-slice in BK
      const int chunk = kh * 4 + quad;     // As swizzle chunk
      half8 aw[2], bf[2];
#pragma unroll
      for (int i = 0; i < 2; ++i) {
        const int r = wmt + i * 16 + frow;
        aw[i] = *(const half8*)&As[cb][(r << 6) + ((chunk ^ (r & 7)) << 3)];
      }
#pragma unroll
      for (int j = 0; j < 2; ++j)
        bf[j] = *(const half8*)&Bs[cb][wnf + j * 16 + frow][kk];
#pragma unroll
      for (int bi = 0; bi < 4; ++bi) {
        const half8 sgv = *(const half8*)&Sg[cb][bi][kk];  // quad-broadcast
        const half8 a0 = aw[0] * sgv;
        const half8 a1 = aw[1] * sgv;
        acc[bi][0][0] = __builtin_amdgcn_mfma_f32_16x16x32_f16(a0, bf[0],
                                                               acc[bi][0][0], 0, 0, 0);
        acc[bi][0][1] = __builtin_amdgcn_mfma_f32_16x16x32_f16(a0, bf[1],
                                                               acc[bi][0][1], 0, 0, 0);
        acc[bi][1][0] = __builtin_amdgcn_mfma_f32_16x16x32_f16(a1, bf[0],
                                                               acc[bi][1][0], 0, 0, 0);
        acc[bi][1][1] = __builtin_amdgcn_mfma_f32_16x16x32_f16(a1, bf[1],
                                                               acc[bi][1][1], 0, 0, 0);
      }
    }
    if (s + 1 < STEPS) STAGE(s + 1, nb);
  }

  // partial[kc][b][f][t]; D frag: col(f)=lane&15, row(t)=(lane>>4)*4+reg
  const int tq = quad * 4;
#pragma unroll
  for (int bi = 0; bi < 4; ++bi) {
    float* pbase = partial + ((size_t)(kc * B_ + bgrp * 4 + bi) << 14);
#pragma unroll
    for (int i = 0; i < 2; ++i) {
      const int t = thalf * 64 + wmt + i * 16 + tq;
#pragma unroll
      for (int j = 0; j < 2; ++j) {
        const int f = fhalf * 64 + wnf + j * 16 + frow;
        *(float4v*)(pbase + f * 128 + t) = acc[bi][i][j];
      }
    }
  }
}

__global__ __launch_bounds__(256) void gabor_reduce_kernel(
    const float* __restrict__ partial, float* __restrict__ out) {
  const size_t gi = ((size_t)blockIdx.x * 256 + threadIdx.x) * 4;  // < 524288
  float4v s = (float4v)(0.0f);
#pragma unroll
  for (int kc = 0; kc < SPLITK; ++kc)
    s += *(const float4v*)(partial + (size_t)kc * 524288 + gi);
  *(float4v*)(out + gi) = s;
}

extern "C" void kernel_launch(void* const* d_in, const int* in_sizes, int n_in,
                              void* d_out, int out_size, void* d_ws, size_t ws_size,
                              hipStream_t stream) {
  const float* signal = (const float*)d_in[0];
  float* out = (float*)d_out;
  float* partial = (float*)d_ws;
  gabor_gemm_kernel<<<dim3(512), dim3(256), 0, stream>>>(signal, partial);
  gabor_reduce_kernel<<<dim3(512), dim3(256), 0, stream>>>(partial, out);
}

// Round 8
// 82.017 us; speedup vs baseline: 2.7114x; 1.0532x over previous
//
#include <hip/hip_runtime.h>
#include <hip/hip_bf16.h>
#include <math.h>

// out[b,f,t] = sum_l sig[b,l] * win[t,l] * cos(2*pi*fv[f]*l/8192)
// Split-K f16 MFMA GEMM, 4-b amortization (R6 structure).
// R8 = R7 with the cvt_pkrtz type fix (__fp16 vec2 return type).
// Transcendental-free table staging: Chebyshev recurrence for cos (exact
// integer phase mod 8192, re-seeded every step), multiplicative recurrence
// for the Gaussian, pkrtz packing.
// fv/tc = linspace->int32 reproduced exactly in fp32 (R0-verified).

#define L_ 8192
#define B_ 32
#define SPLITK 16
#define KCHUNK 512   // L_/SPLITK
#define BK 64
#define STEPS 8      // KCHUNK/BK

typedef _Float16 half8 __attribute__((ext_vector_type(8)));
typedef __fp16 fp16x2 __attribute__((ext_vector_type(2)));
typedef float float4v __attribute__((ext_vector_type(4)));

#define H_ 0.001220703125f            // 1/819.2 (exact)
#define H64_ 0.078125f                // 64/819.2 (exact)
#define QQ_ 0.99999850988388061523f   // exp(-H^2)
#define CSTEP_ 7.66990393942594528198e-4f  // 2*pi/8192

// ws: [0,32MB) partial [16 kc][32 b][128 f][128 t] fp32

__global__ __launch_bounds__(256, 3) void gabor_gemm_kernel(
    const float* __restrict__ signal, float* __restrict__ partial) {
  const int bx = blockIdx.x;          // 512 blocks
  const int fhalf = bx & 1;
  const int thalf = (bx >> 1) & 1;
  const int bgrp = (bx >> 2) & 7;     // group of 4 b's
  const int kc = bx >> 5;             // 0..15
  const int tid = threadIdx.x;

  __shared__ _Float16 As[2][64 * 64];   // win rows(t), XOR-swizzled, 8 KB ea
  __shared__ _Float16 Bs[2][64][72];    // cos rows(f), +8 pad, 9 KB ea
  __shared__ _Float16 Sg[2][4][64];     // sig f16 per b

  const int lane = tid & 63;
  const int wv = tid >> 6;
  const int wmt = (wv >> 1) * 32;  // t quadrant (32)
  const int wnf = (wv & 1) * 32;   // f quadrant (32)
  const int frow = lane & 15;
  const int quad = lane >> 4;

  const int r0 = tid >> 3;       // staging row 0..31 (+32 for rep 1)
  const int c8 = (tid & 7) * 8;  // col base 0..56
  const int cidx = tid & 7;      // chunk index for As swizzle

  const float tstep = 8191.0f / 127.0f;
  const float fstep = 4096.0f / 127.0f;
  const int l0f = kc * KCHUNK;

  // per-rep staging state (advanced each step)
  float x[2];    // (l - tc) / sigma_w at e=0
  int m[2];      // (fv * l) mod 8192 at e=0 (exact integer phase)
  int dfv[2];    // (fv<<6) per-step phase increment
  float dlt[2];  // delta = fv * cstep
  float k2[2];   // 2*cos(delta)  (Chebyshev coefficient)
#pragma unroll
  for (int rep = 0; rep < 2; ++rep) {
    const int row = r0 + rep * 32;
    const float tc = truncf((float)(thalf * 64 + row) * tstep);
    const int fv = (int)((float)(fhalf * 64 + row) * fstep);
    x[rep] = ((float)(l0f + c8) - tc) * H_;
    m[rep] = __mul24(fv, l0f + c8) & (L_ - 1);
    dfv[rep] = fv << 6;
    dlt[rep] = (float)fv * CSTEP_;
    k2[rep] = 2.0f * __cosf(dlt[rep]);
  }

  float4v acc[4][2][2];
#pragma unroll
  for (int bi = 0; bi < 4; ++bi)
#pragma unroll
    for (int i = 0; i < 2; ++i)
#pragma unroll
      for (int j = 0; j < 2; ++j) acc[bi][i][j] = (float4v)(0.0f);

  const float* sigbase = signal + (size_t)(bgrp * 4) * L_;

  union H8 {
    fp16x2 h2[4];
    half8 h8;
  };

  // Stage win/cos/sig tiles for K-step s into buffer buf; advances x/m state.
#define STAGE(s, buf)                                                        \
  {                                                                          \
    const int l0 = l0f + (s)*BK;                                             \
    Sg[buf][wv][lane] = (_Float16)sigbase[(size_t)wv * L_ + l0 + lane];      \
    _Pragma("unroll") for (int rep = 0; rep < 2; ++rep) {                    \
      const int row = r0 + rep * 32;                                         \
      /* gaussian: w[e] = w[e-1]*ratio, ratio *= Q */                        \
      float w0 = __expf(-0.5f * x[rep] * x[rep]);                            \
      float ratio = __expf(-H_ * (x[rep] + 0.5f * H_));                      \
      /* cos: Chebyshev from two exact-phase seeds */                        \
      const float a = (float)m[rep] * CSTEP_;                                \
      float cm2 = __cosf(a);                                                 \
      float cm1 = __cosf(a + dlt[rep]);                                      \
      H8 hw, hb;                                                             \
      float wp = w0;                                                         \
      float wn = w0 * ratio;                                                 \
      ratio *= QQ_;                                                          \
      hw.h2[0] = __builtin_amdgcn_cvt_pkrtz(wp, wn);                         \
      hb.h2[0] = __builtin_amdgcn_cvt_pkrtz(cm2, cm1);                       \
      _Pragma("unroll") for (int p = 1; p < 4; ++p) {                        \
        wp = wn * ratio;                                                     \
        ratio *= QQ_;                                                        \
        wn = wp * ratio;                                                     \
        ratio *= QQ_;                                                        \
        hw.h2[p] = __builtin_amdgcn_cvt_pkrtz(wp, wn);                       \
        const float c0 = __builtin_fmaf(k2[rep], cm1, -cm2);                 \
        const float c1 = __builtin_fmaf(k2[rep], c0, -cm1);                  \
        hb.h2[p] = __builtin_amdgcn_cvt_pkrtz(c0, c1);                       \
        cm2 = c0;                                                            \
        cm1 = c1;                                                            \
      }                                                                      \
      *(half8*)&As[buf][(row << 6) + ((cidx ^ (row & 7)) << 3)] = hw.h8;     \
      *(half8*)&Bs[buf][row][c8] = hb.h8;                                    \
      x[rep] += H64_;                                                        \
      m[rep] = (m[rep] + dfv[rep]) & (L_ - 1);                               \
    }                                                                        \
  }

  STAGE(0, 0);

  for (int s = 0; s < STEPS; ++s) {
    const int cb = s & 1, nb = cb ^ 1;
    __syncthreads();  // buf cb complete
#pragma unroll
    for (int kh = 0; kh < 2; ++kh) {
      const int kk = kh * 32 + quad * 8;   // k-slice in BK
      const int chunk = kh * 4 + quad;     // As swizzle chunk
      half8 aw[2], bf[2];
#pragma unroll
      for (int i = 0; i < 2; ++i) {
        const int r = wmt + i * 16 + frow;
        aw[i] = *(const half8*)&As[cb][(r << 6) + ((chunk ^ (r & 7)) << 3)];
      }
#pragma unroll
      for (int j = 0; j < 2; ++j)
        bf[j] = *(const half8*)&Bs[cb][wnf + j * 16 + frow][kk];
#pragma unroll
      for (int bi = 0; bi < 4; ++bi) {
        const half8 sgv = *(const half8*)&Sg[cb][bi][kk];  // quad-broadcast
        const half8 a0 = aw[0] * sgv;
        const half8 a1 = aw[1] * sgv;
        acc[bi][0][0] = __builtin_amdgcn_mfma_f32_16x16x32_f16(a0, bf[0],
                                                               acc[bi][0][0], 0, 0, 0);
        acc[bi][0][1] = __builtin_amdgcn_mfma_f32_16x16x32_f16(a0, bf[1],
                                                               acc[bi][0][1], 0, 0, 0);
        acc[bi][1][0] = __builtin_amdgcn_mfma_f32_16x16x32_f16(a1, bf[0],
                                                               acc[bi][1][0], 0, 0, 0);
        acc[bi][1][1] = __builtin_amdgcn_mfma_f32_16x16x32_f16(a1, bf[1],
                                                               acc[bi][1][1], 0, 0, 0);
      }
    }
    if (s + 1 < STEPS) STAGE(s + 1, nb);
  }

  // partial[kc][b][f][t]; D frag: col(f)=lane&15, row(t)=(lane>>4)*4+reg
  const int tq = quad * 4;
#pragma unroll
  for (int bi = 0; bi < 4; ++bi) {
    float* pbase = partial + ((size_t)(kc * B_ + bgrp * 4 + bi) << 14);
#pragma unroll
    for (int i = 0; i < 2; ++i) {
      const int t = thalf * 64 + wmt + i * 16 + tq;
#pragma unroll
      for (int j = 0; j < 2; ++j) {
        const int f = fhalf * 64 + wnf + j * 16 + frow;
        *(float4v*)(pbase + f * 128 + t) = acc[bi][i][j];
      }
    }
  }
}

__global__ __launch_bounds__(256) void gabor_reduce_kernel(
    const float* __restrict__ partial, float* __restrict__ out) {
  const size_t gi = ((size_t)blockIdx.x * 256 + threadIdx.x) * 4;  // < 524288
  float4v s = (float4v)(0.0f);
#pragma unroll
  for (int kc = 0; kc < SPLITK; ++kc)
    s += *(const float4v*)(partial + (size_t)kc * 524288 + gi);
  *(float4v*)(out + gi) = s;
}

extern "C" void kernel_launch(void* const* d_in, const int* in_sizes, int n_in,
                              void* d_out, int out_size, void* d_ws, size_t ws_size,
                              hipStream_t stream) {
  const float* signal = (const float*)d_in[0];
  float* out = (float*)d_out;
  float* partial = (float*)d_ws;
  gabor_gemm_kernel<<<dim3(512), dim3(256), 0, stream>>>(signal, partial);
  gabor_reduce_kernel<<<dim3(512), dim3(256), 0, stream>>>(partial, out);
}

// Round 9
// 81.286 us; speedup vs baseline: 2.7357x; 1.0090x over previous
//
#include <hip/hip_runtime.h>
#include <hip/hip_bf16.h>
#include <math.h>

// out[b,f,t] = sum_l sig[b,l] * win[t,l] * cos(2*pi*fv[f]*l/8192)
// Split-K f16 MFMA GEMM, 4-b amortization. R9: latency attack —
// 1024 blocks (4/CU, 64t x 32f tiles), sig hoisted to LDS before the K-loop
// (steady-state loop touches LDS only; no vmcnt in the barrier drain),
// transcendental-free staging recurrences (R8-proven).
// fv/tc = linspace->int32 reproduced exactly in fp32 (R0-verified).

#define L_ 8192
#define B_ 32
#define SPLITK 16
#define KCHUNK 512   // L_/SPLITK
#define BK 64
#define STEPS 8      // KCHUNK/BK

typedef _Float16 half8 __attribute__((ext_vector_type(8)));
typedef __fp16 fp16x2 __attribute__((ext_vector_type(2)));
typedef float float4v __attribute__((ext_vector_type(4)));

#define H_ 0.001220703125f            // 1/819.2 (exact)
#define H64_ 0.078125f                // 64/819.2 (exact)
#define QQ_ 0.99999850988388061523f   // exp(-H^2)
#define CSTEP_ 7.66990393942594528198e-4f  // 2*pi/8192

// ws: [0,32MB) partial [16 kc][32 b][128 f][128 t] fp32

__global__ __launch_bounds__(256, 4) void gabor_gemm_kernel(
    const float* __restrict__ signal, float* __restrict__ partial) {
  const int bx = blockIdx.x;          // 1024 blocks
  const int fq = bx & 3;              // f quarter (32 rows)
  const int tq64 = (bx >> 2) & 1;     // t half (64 rows)
  const int bgrp = (bx >> 3) & 7;     // group of 4 b's
  const int kc = bx >> 6;             // 0..15
  const int tid = threadIdx.x;

  __shared__ _Float16 As[2][64 * 64];   // win rows(t), XOR-swizzled, 8 KB ea
  __shared__ _Float16 Bs[2][32][72];    // cos rows(f), +8 pad, 4.6 KB ea
  __shared__ _Float16 Sg[4][KCHUNK];    // sig f16 per b, whole K-chunk, 4 KB

  const int lane = tid & 63;
  const int wv = tid >> 6;
  const int wmt = (wv & 1) * 32;   // t sub-tile (32)
  const int wnf = (wv >> 1) * 16;  // f sub-tile (16)
  const int frow = lane & 15;
  const int quad = lane >> 4;

  const int r0 = tid >> 3;       // staging row 0..31
  const int c8 = (tid & 7) * 8;  // col base 0..56
  const int cidx = tid & 7;      // chunk index for As swizzle

  const float tstep = 8191.0f / 127.0f;
  const float fstep = 4096.0f / 127.0f;
  const int l0f = kc * KCHUNK;

  // ---- one-time sig -> LDS (4 b x 512 K) ----
  {
    const int bi = tid >> 6;          // 0..3
    const int e8 = (tid & 63) * 8;    // 0..504
    const float* sp = signal + (size_t)(bgrp * 4 + bi) * L_ + l0f + e8;
    union { fp16x2 h2[4]; half8 h8; } sh;
#pragma unroll
    for (int p = 0; p < 4; ++p)
      sh.h2[p] = __builtin_amdgcn_cvt_pkrtz(sp[2 * p], sp[2 * p + 1]);
    *(half8*)&Sg[bi][e8] = sh.h8;
  }

  // per-thread staging state (advanced each step)
  // win: 2 reps (rows r0, r0+32); cos: 1 rep (row r0)
  float x[2];
  int m, dfv;
  float dlt, k2;
#pragma unroll
  for (int rep = 0; rep < 2; ++rep) {
    const float tc = truncf((float)(tq64 * 64 + r0 + rep * 32) * tstep);
    x[rep] = ((float)(l0f + c8) - tc) * H_;
  }
  {
    const int fv = (int)((float)(fq * 32 + r0) * fstep);
    m = __mul24(fv, l0f + c8) & (L_ - 1);
    dfv = fv << 6;
    dlt = (float)fv * CSTEP_;
    k2 = 2.0f * __cosf(dlt);
  }

  float4v acc[4][2];
#pragma unroll
  for (int bi = 0; bi < 4; ++bi)
#pragma unroll
    for (int i = 0; i < 2; ++i) acc[bi][i] = (float4v)(0.0f);

  union H8 { fp16x2 h2[4]; half8 h8; };

  // Stage win (2 reps) + cos (1 rep) for K-step s into buffer buf.
#define STAGE(s, buf)                                                        \
  {                                                                          \
    _Pragma("unroll") for (int rep = 0; rep < 2; ++rep) {                    \
      const int row = r0 + rep * 32;                                         \
      float w0 = __expf(-0.5f * x[rep] * x[rep]);                            \
      float ratio = __expf(-H_ * (x[rep] + 0.5f * H_));                      \
      H8 hw;                                                                 \
      float wp = w0;                                                         \
      float wn = w0 * ratio;                                                 \
      ratio *= QQ_;                                                          \
      hw.h2[0] = __builtin_amdgcn_cvt_pkrtz(wp, wn);                         \
      _Pragma("unroll") for (int p = 1; p < 4; ++p) {                        \
        wp = wn * ratio;                                                     \
        ratio *= QQ_;                                                        \
        wn = wp * ratio;                                                     \
        ratio *= QQ_;                                                        \
        hw.h2[p] = __builtin_amdgcn_cvt_pkrtz(wp, wn);                       \
      }                                                                      \
      *(half8*)&As[buf][(row << 6) + ((cidx ^ (row & 7)) << 3)] = hw.h8;     \
      x[rep] += H64_;                                                        \
    }                                                                        \
    {                                                                        \
      const float a = (float)m * CSTEP_;                                     \
      float cm2 = __cosf(a);                                                 \
      float cm1 = __cosf(a + dlt);                                           \
      H8 hb;                                                                 \
      hb.h2[0] = __builtin_amdgcn_cvt_pkrtz(cm2, cm1);                       \
      _Pragma("unroll") for (int p = 1; p < 4; ++p) {                        \
        const float c0 = __builtin_fmaf(k2, cm1, -cm2);                      \
        const float c1 = __builtin_fmaf(k2, c0, -cm1);                       \
        hb.h2[p] = __builtin_amdgcn_cvt_pkrtz(c0, c1);                       \
        cm2 = c0;                                                            \
        cm1 = c1;                                                            \
      }                                                                      \
      *(half8*)&Bs[buf][r0][c8] = hb.h8;                                     \
      m = (m + dfv) & (L_ - 1);                                              \
    }                                                                        \
  }

  STAGE(0, 0);

  for (int s = 0; s < STEPS; ++s) {
    const int cb = s & 1, nb = cb ^ 1;
    __syncthreads();  // buf cb complete (LDS-only drain in steady state)
#pragma unroll
    for (int kh = 0; kh < 2; ++kh) {
      const int kk = kh * 32 + quad * 8;   // k-slice in BK
      const int chunk = kh * 4 + quad;     // As swizzle chunk
      half8 aw[2], bf;
#pragma unroll
      for (int i = 0; i < 2; ++i) {
        const int r = wmt + i * 16 + frow;
        aw[i] = *(const half8*)&As[cb][(r << 6) + ((chunk ^ (r & 7)) << 3)];
      }
      bf = *(const half8*)&Bs[cb][wnf + frow][kk];
#pragma unroll
      for (int bi = 0; bi < 4; ++bi) {
        const half8 sgv = *(const half8*)&Sg[bi][s * BK + kk];  // broadcast
        const half8 a0 = aw[0] * sgv;
        const half8 a1 = aw[1] * sgv;
        acc[bi][0] = __builtin_amdgcn_mfma_f32_16x16x32_f16(a0, bf,
                                                            acc[bi][0], 0, 0, 0);
        acc[bi][1] = __builtin_amdgcn_mfma_f32_16x16x32_f16(a1, bf,
                                                            acc[bi][1], 0, 0, 0);
      }
    }
    if (s + 1 < STEPS) STAGE(s + 1, nb);
  }

  // partial[kc][b][f][t]; D frag: col(f)=lane&15, row(t)=(lane>>4)*4+reg
  const int tqr = quad * 4;
#pragma unroll
  for (int bi = 0; bi < 4; ++bi) {
    float* pbase = partial + ((size_t)(kc * B_ + bgrp * 4 + bi) << 14);
    const int f = fq * 32 + wnf + frow;
#pragma unroll
    for (int i = 0; i < 2; ++i) {
      const int t = tq64 * 64 + wmt + i * 16 + tqr;
      *(float4v*)(pbase + f * 128 + t) = acc[bi][i];
    }
  }
}

__global__ __launch_bounds__(256) void gabor_reduce_kernel(
    const float* __restrict__ partial, float* __restrict__ out) {
  const size_t gi = ((size_t)blockIdx.x * 256 + threadIdx.x) * 4;  // < 524288
  float4v s = (float4v)(0.0f);
#pragma unroll
  for (int kc = 0; kc < SPLITK; ++kc)
    s += *(const float4v*)(partial + (size_t)kc * 524288 + gi);
  *(float4v*)(out + gi) = s;
}

extern "C" void kernel_launch(void* const* d_in, const int* in_sizes, int n_in,
                              void* d_out, int out_size, void* d_ws, size_t ws_size,
                              hipStream_t stream) {
  const float* signal = (const float*)d_in[0];
  float* out = (float*)d_out;
  float* partial = (float*)d_ws;
  gabor_gemm_kernel<<<dim3(1024), dim3(256), 0, stream>>>(signal, partial);
  gabor_reduce_kernel<<<dim3(512), dim3(256), 0, stream>>>(partial, out);
}

// Round 10
// 81.166 us; speedup vs baseline: 2.7398x; 1.0015x over previous
//
#include <hip/hip_runtime.h>
#include <hip/hip_bf16.h>
#include <math.h>

// out[b,f,t] = sum_l sig[b,l] * win[t,l] * cos(2*pi*fv[f]*l/8192)
// R10: barrier-free register-direct GEMM. Each lane generates its own MFMA
// A/B fragment elements via per-lane recurrences (Gaussian: multiplicative;
// cos: stride-32 Chebyshev pair, seeded from exact integer phase mod 8192).
// No LDS A/B tiles, no K-loop __syncthreads (kills the convoy stalls that
// made R5-R9 insensitive to VALU/occupancy changes). Only sig lives in LDS
// (4 KB, staged once). Wave tile: 32t x 32f x 4b, split-K 16.
// fv/tc = linspace->int32 reproduced exactly in fp32 (R0-verified).

#define L_ 8192
#define B_ 32
#define SPLITK 16
#define KW 512       // K per wave (L_/SPLITK)
#define NSTEP 16     // KW/32

typedef _Float16 half8 __attribute__((ext_vector_type(8)));
typedef __fp16 fp16x2 __attribute__((ext_vector_type(2)));
typedef float float4v __attribute__((ext_vector_type(4)));

#define H_ 0.001220703125f                 // 1/819.2 = 5/4096 (exact)
#define CSTEP_ 7.66990393942594528198e-4f  // 2*pi/8192

// ws: [0,32MB) partial [16 kc][32 b][128 f][128 t] fp32

__global__ __launch_bounds__(256, 2) void gabor_gemm_kernel(
    const float* __restrict__ signal, float* __restrict__ partial) {
  const int bx = blockIdx.x;   // 512 = kc16 * bgrp8 * tile4
  const int kc = bx & 15;
  const int bgrp = (bx >> 4) & 7;
  const int th = (bx >> 7) & 1;
  const int fh = (bx >> 8) & 1;
  const int tid = threadIdx.x;
  const int lane = tid & 63;
  const int wv = tid >> 6;
  const int frow = lane & 15;
  const int quad = lane >> 4;

  __shared__ _Float16 Sg[4][KW];  // sig f16 per b, 4 KB

  // ---- one-time sig -> LDS ----
  {
    const int idx = tid * 8;  // 0..2040
    const int bi = idx >> 9;
    const int off = idx & 511;
    const float* sp = signal + (size_t)(bgrp * 4 + bi) * L_ + kc * KW + off;
    float4v s0 = *(const float4v*)sp;
    float4v s1 = *(const float4v*)(sp + 4);
    union { fp16x2 h2[4]; half8 h8; } sh;
    sh.h2[0] = __builtin_amdgcn_cvt_pkrtz(s0[0], s0[1]);
    sh.h2[1] = __builtin_amdgcn_cvt_pkrtz(s0[2], s0[3]);
    sh.h2[2] = __builtin_amdgcn_cvt_pkrtz(s1[0], s1[1]);
    sh.h2[3] = __builtin_amdgcn_cvt_pkrtz(s1[2], s1[3]);
    *(half8*)&Sg[bi][off] = sh.h8;
  }
  __syncthreads();  // the ONLY barrier

  const int t0 = th * 64 + (wv & 1) * 32;
  const int f0 = fh * 64 + (wv >> 1) * 32;
  const int l0 = kc * KW + quad * 8;  // k of element j=0 at step 0

  // ---- per-lane fragment state ----
  // A (win): w[fr][j] = exp(-0.5*x^2); advance k+=32: w *= Rw, Rw *= Q32
  float w[2][8], Rw[2][8];
  const float Q32 = __expf(-0.00152587890625f);  // exp(-1024*H^2)
#pragma unroll
  for (int fr = 0; fr < 2; ++fr) {
    const float tc = truncf((float)(t0 + fr * 16 + frow) * (8191.0f / 127.0f));
#pragma unroll
    for (int j = 0; j < 8; ++j) {
      const float x = ((float)(l0 + j) - tc) * H_;
      w[fr][j] = __expf(-0.5f * x * x);
      // Rw = exp(-32*H*x - 512*H^2)
      Rw[fr][j] = __expf(__builtin_fmaf(-0.0390625f, x, -7.62939453125e-4f));
    }
  }
  // B (cos): stride-32 Chebyshev pair per j, exact integer phase seeds
  float c[2][8], cp[2][8], K32[2];
#pragma unroll
  for (int fr = 0; fr < 2; ++fr) {
    const int fv = (int)((float)(f0 + fr * 16 + frow) * (4096.0f / 127.0f));
    K32[fr] = 2.0f * __cosf((float)((fv * 32) & (L_ - 1)) * CSTEP_);
#pragma unroll
    for (int j = 0; j < 8; ++j) {
      c[fr][j] = __cosf((float)((fv * (l0 + j)) & (L_ - 1)) * CSTEP_);
      // cp at k-32  (l0+j+8160 == l0+j-32 mod 8192)
      cp[fr][j] = __cosf((float)((fv * (l0 + j + 8160)) & (L_ - 1)) * CSTEP_);
    }
  }

  float4v acc[2][2][4];  // [fr1 t][fr2 f][bi]
#pragma unroll
  for (int i = 0; i < 2; ++i)
#pragma unroll
    for (int j = 0; j < 2; ++j)
#pragma unroll
      for (int bi = 0; bi < 4; ++bi) acc[i][j][bi] = (float4v)(0.0f);

  // ---- barrier-free K loop ----
#pragma unroll
  for (int s = 0; s < NSTEP; ++s) {
    union { fp16x2 h2[4]; half8 h8; } ha[2], hc[2];
#pragma unroll
    for (int fr = 0; fr < 2; ++fr)
#pragma unroll
      for (int p = 0; p < 4; ++p) {
        ha[fr].h2[p] = __builtin_amdgcn_cvt_pkrtz(w[fr][2 * p], w[fr][2 * p + 1]);
        hc[fr].h2[p] = __builtin_amdgcn_cvt_pkrtz(c[fr][2 * p], c[fr][2 * p + 1]);
      }
    half8 sgv[4];
#pragma unroll
    for (int bi = 0; bi < 4; ++bi)
      sgv[bi] = *(const half8*)&Sg[bi][s * 32 + quad * 8];  // quad broadcast
#pragma unroll
    for (int fr2 = 0; fr2 < 2; ++fr2)
#pragma unroll
      for (int bi = 0; bi < 4; ++bi) {
        const half8 hbf = hc[fr2].h8 * sgv[bi];  // fold sig into B-frag
        acc[0][fr2][bi] = __builtin_amdgcn_mfma_f32_16x16x32_f16(
            ha[0].h8, hbf, acc[0][fr2][bi], 0, 0, 0);
        acc[1][fr2][bi] = __builtin_amdgcn_mfma_f32_16x16x32_f16(
            ha[1].h8, hbf, acc[1][fr2][bi], 0, 0, 0);
      }
    if (s + 1 < NSTEP) {
#pragma unroll
      for (int fr = 0; fr < 2; ++fr)
#pragma unroll
        for (int j = 0; j < 8; ++j) {
          w[fr][j] *= Rw[fr][j];
          Rw[fr][j] *= Q32;
          const float cn = __builtin_fmaf(K32[fr], c[fr][j], -cp[fr][j]);
          cp[fr][j] = c[fr][j];
          c[fr][j] = cn;
        }
    }
  }

  // partial[kc][b][f][t]; D frag: col(f)=lane&15, row(t)=quad*4+reg
#pragma unroll
  for (int bi = 0; bi < 4; ++bi) {
    float* pbase = partial + ((size_t)(kc * B_ + bgrp * 4 + bi) << 14);
#pragma unroll
    for (int fr2 = 0; fr2 < 2; ++fr2) {
      const int f = f0 + fr2 * 16 + frow;
#pragma unroll
      for (int fr1 = 0; fr1 < 2; ++fr1) {
        const int t = t0 + fr1 * 16 + quad * 4;
        *(float4v*)(pbase + f * 128 + t) = acc[fr1][fr2][bi];
      }
    }
  }
}

__global__ __launch_bounds__(256) void gabor_reduce_kernel(
    const float* __restrict__ partial, float* __restrict__ out) {
  const size_t gi = ((size_t)blockIdx.x * 256 + threadIdx.x) * 4;  // < 524288
  float4v s = (float4v)(0.0f);
#pragma unroll
  for (int kc = 0; kc < SPLITK; ++kc)
    s += *(const float4v*)(partial + (size_t)kc * 524288 + gi);
  *(float4v*)(out + gi) = s;
}

extern "C" void kernel_launch(void* const* d_in, const int* in_sizes, int n_in,
                              void* d_out, int out_size, void* d_ws, size_t ws_size,
                              hipStream_t stream) {
  const float* signal = (const float*)d_in[0];
  float* out = (float*)d_out;
  float* partial = (float*)d_ws;
  gabor_gemm_kernel<<<dim3(512), dim3(256), 0, stream>>>(signal, partial);
  gabor_reduce_kernel<<<dim3(512), dim3(256), 0, stream>>>(partial, out);
}

// Round 11
// 80.684 us; speedup vs baseline: 2.7562x; 1.0060x over previous
//
#include <hip/hip_runtime.h>
#include <hip/hip_bf16.h>
#include <math.h>

// out[b,f,t] = sum_l sig[b,l] * win[t,l] * cos(2*pi*fv[f]*l/8192)
// R11 = R10 (barrier-free register-direct split-K MFMA GEMM) with:
//  - ROLLED K-loop (8 iters x 2 sub-steps, #pragma unroll 1): small I-footprint,
//    bounded live ranges (R10 fully unrolled 16 steps -> possible scratch spill
//    under the (256,2) 256-VGPR cap; spills = invisible global traffic).
//  - __launch_bounds__(256,1): 512-VGPR cap, spill-proof; est ~190 live so
//    2 blocks/CU occupancy is preserved.
//  - Ping-pong Chebyshev (in-place FMA, no moves).
// fv/tc = linspace->int32 reproduced exactly in fp32 (R0-verified).

#define L_ 8192
#define B_ 32
#define SPLITK 16
#define KW 512       // K per wave (L_/SPLITK)

typedef _Float16 half8 __attribute__((ext_vector_type(8)));
typedef __fp16 fp16x2 __attribute__((ext_vector_type(2)));
typedef float float4v __attribute__((ext_vector_type(4)));

#define H_ 0.001220703125f                 // 1/819.2 = 5/4096 (exact)
#define CSTEP_ 7.66990393942594528198e-4f  // 2*pi/8192

// ws: [0,32MB) partial [16 kc][32 b][128 f][128 t] fp32

__global__ __launch_bounds__(256, 1) void gabor_gemm_kernel(
    const float* __restrict__ signal, float* __restrict__ partial) {
  const int bx = blockIdx.x;   // 512 = kc16 * bgrp8 * tile4
  const int kc = bx & 15;
  const int bgrp = (bx >> 4) & 7;
  const int th = (bx >> 7) & 1;
  const int fh = (bx >> 8) & 1;
  const int tid = threadIdx.x;
  const int lane = tid & 63;
  const int wv = tid >> 6;
  const int frow = lane & 15;
  const int quad = lane >> 4;

  __shared__ _Float16 Sg[4][KW];  // sig f16 per b, 4 KB

  // ---- one-time sig -> LDS ----
  {
    const int idx = tid * 8;  // 0..2040
    const int bi = idx >> 9;
    const int off = idx & 511;
    const float* sp = signal + (size_t)(bgrp * 4 + bi) * L_ + kc * KW + off;
    float4v s0 = *(const float4v*)sp;
    float4v s1 = *(const float4v*)(sp + 4);
    union { fp16x2 h2[4]; half8 h8; } sh;
    sh.h2[0] = __builtin_amdgcn_cvt_pkrtz(s0[0], s0[1]);
    sh.h2[1] = __builtin_amdgcn_cvt_pkrtz(s0[2], s0[3]);
    sh.h2[2] = __builtin_amdgcn_cvt_pkrtz(s1[0], s1[1]);
    sh.h2[3] = __builtin_amdgcn_cvt_pkrtz(s1[2], s1[3]);
    *(half8*)&Sg[bi][off] = sh.h8;
  }
  __syncthreads();  // the ONLY barrier

  const int t0 = th * 64 + (wv & 1) * 32;
  const int f0 = fh * 64 + (wv >> 1) * 32;
  const int l0 = kc * KW + quad * 8;  // k of element j=0 at step 0

  // ---- per-lane fragment state ----
  // A (win): w[fr][j] = exp(-0.5*x^2); advance k+=32: w *= Rw, Rw *= Q32
  float w[2][8], Rw[2][8];
  const float Q32 = __expf(-0.00152587890625f);  // exp(-1024*H^2)
#pragma unroll
  for (int fr = 0; fr < 2; ++fr) {
    const float tc = truncf((float)(t0 + fr * 16 + frow) * (8191.0f / 127.0f));
#pragma unroll
    for (int j = 0; j < 8; ++j) {
      const float x = ((float)(l0 + j) - tc) * H_;
      w[fr][j] = __expf(-0.5f * x * x);
      // Rw = exp(-32*H*x - 512*H^2)
      Rw[fr][j] = __expf(__builtin_fmaf(-0.0390625f, x, -7.62939453125e-4f));
    }
  }
  // B (cos): stride-32 Chebyshev ping-pong (cE = even-step value, cO = value
  // one stride behind; after even step cO <- next odd value, etc.)
  float cE[2][8], cO[2][8], K32[2];
#pragma unroll
  for (int fr = 0; fr < 2; ++fr) {
    const int fv = (int)((float)(f0 + fr * 16 + frow) * (4096.0f / 127.0f));
    K32[fr] = 2.0f * __cosf((float)((fv * 32) & (L_ - 1)) * CSTEP_);
#pragma unroll
    for (int j = 0; j < 8; ++j) {
      cE[fr][j] = __cosf((float)((fv * (l0 + j)) & (L_ - 1)) * CSTEP_);
      // value at k-32  (l0+j+8160 == l0+j-32 mod 8192)
      cO[fr][j] = __cosf((float)((fv * (l0 + j + 8160)) & (L_ - 1)) * CSTEP_);
    }
  }

  float4v acc[2][2][4];  // [fr1 t][fr2 f][bi]
#pragma unroll
  for (int i = 0; i < 2; ++i)
#pragma unroll
    for (int j = 0; j < 2; ++j)
#pragma unroll
      for (int bi = 0; bi < 4; ++bi) acc[i][j][bi] = (float4v)(0.0f);

  union H8 { fp16x2 h2[4]; half8 h8; };

  // ---- rolled, barrier-free K loop: 8 iterations x 2 sub-steps ----
#pragma unroll 1
  for (int p = 0; p < 8; ++p) {
    half8 sgA[4], sgB[4];
#pragma unroll
    for (int bi = 0; bi < 4; ++bi) {
      sgA[bi] = *(const half8*)&Sg[bi][(2 * p) * 32 + quad * 8];
      sgB[bi] = *(const half8*)&Sg[bi][(2 * p + 1) * 32 + quad * 8];
    }
    // -- even sub-step: fragments from w, cE --
    {
      H8 ha[2], hc[2];
#pragma unroll
      for (int fr = 0; fr < 2; ++fr)
#pragma unroll
        for (int q = 0; q < 4; ++q) {
          ha[fr].h2[q] = __builtin_amdgcn_cvt_pkrtz(w[fr][2 * q], w[fr][2 * q + 1]);
          hc[fr].h2[q] = __builtin_amdgcn_cvt_pkrtz(cE[fr][2 * q], cE[fr][2 * q + 1]);
        }
#pragma unroll
      for (int fr2 = 0; fr2 < 2; ++fr2)
#pragma unroll
        for (int bi = 0; bi < 4; ++bi) {
          const half8 hbf = hc[fr2].h8 * sgA[bi];
          acc[0][fr2][bi] = __builtin_amdgcn_mfma_f32_16x16x32_f16(
              ha[0].h8, hbf, acc[0][fr2][bi], 0, 0, 0);
          acc[1][fr2][bi] = __builtin_amdgcn_mfma_f32_16x16x32_f16(
              ha[1].h8, hbf, acc[1][fr2][bi], 0, 0, 0);
        }
      // advance to odd: w *= Rw; Rw *= Q32; cO <- K32*cE - cO (in place)
#pragma unroll
      for (int fr = 0; fr < 2; ++fr)
#pragma unroll
        for (int j = 0; j < 8; ++j) {
          w[fr][j] *= Rw[fr][j];
          Rw[fr][j] *= Q32;
          cO[fr][j] = __builtin_fmaf(K32[fr], cE[fr][j], -cO[fr][j]);
        }
    }
    // -- odd sub-step: fragments from w, cO --
    {
      H8 ha[2], hc[2];
#pragma unroll
      for (int fr = 0; fr < 2; ++fr)
#pragma unroll
        for (int q = 0; q < 4; ++q) {
          ha[fr].h2[q] = __builtin_amdgcn_cvt_pkrtz(w[fr][2 * q], w[fr][2 * q + 1]);
          hc[fr].h2[q] = __builtin_amdgcn_cvt_pkrtz(cO[fr][2 * q], cO[fr][2 * q + 1]);
        }
#pragma unroll
      for (int fr2 = 0; fr2 < 2; ++fr2)
#pragma unroll
        for (int bi = 0; bi < 4; ++bi) {
          const half8 hbf = hc[fr2].h8 * sgB[bi];
          acc[0][fr2][bi] = __builtin_amdgcn_mfma_f32_16x16x32_f16(
              ha[0].h8, hbf, acc[0][fr2][bi], 0, 0, 0);
          acc[1][fr2][bi] = __builtin_amdgcn_mfma_f32_16x16x32_f16(
              ha[1].h8, hbf, acc[1][fr2][bi], 0, 0, 0);
        }
      // advance to next even: w *= Rw; Rw *= Q32; cE <- K32*cO - cE (in place)
#pragma unroll
      for (int fr = 0; fr < 2; ++fr)
#pragma unroll
        for (int j = 0; j < 8; ++j) {
          w[fr][j] *= Rw[fr][j];
          Rw[fr][j] *= Q32;
          cE[fr][j] = __builtin_fmaf(K32[fr], cO[fr][j], -cE[fr][j]);
        }
    }
  }

  // partial[kc][b][f][t]; D frag: col(f)=lane&15, row(t)=quad*4+reg
#pragma unroll
  for (int bi = 0; bi < 4; ++bi) {
    float* pbase = partial + ((size_t)(kc * B_ + bgrp * 4 + bi) << 14);
#pragma unroll
    for (int fr2 = 0; fr2 < 2; ++fr2) {
      const int f = f0 + fr2 * 16 + frow;
#pragma unroll
      for (int fr1 = 0; fr1 < 2; ++fr1) {
        const int t = t0 + fr1 * 16 + quad * 4;
        *(float4v*)(pbase + f * 128 + t) = acc[fr1][fr2][bi];
      }
    }
  }
}

__global__ __launch_bounds__(256) void gabor_reduce_kernel(
    const float* __restrict__ partial, float* __restrict__ out) {
  const size_t gi = ((size_t)blockIdx.x * 256 + threadIdx.x) * 4;  // < 524288
  float4v s = (float4v)(0.0f);
#pragma unroll
  for (int kc = 0; kc < SPLITK; ++kc)
    s += *(const float4v*)(partial + (size_t)kc * 524288 + gi);
  *(float4v*)(out + gi) = s;
}

extern "C" void kernel_launch(void* const* d_in, const int* in_sizes, int n_in,
                              void* d_out, int out_size, void* d_ws, size_t ws_size,
                              hipStream_t stream) {
  const float* signal = (const float*)d_in[0];
  float* out = (float*)d_out;
  float* partial = (float*)d_ws;
  gabor_gemm_kernel<<<dim3(512), dim3(256), 0, stream>>>(signal, partial);
  gabor_reduce_kernel<<<dim3(512), dim3(256), 0, stream>>>(partial, out);
}

// Round 12
// 70.920 us; speedup vs baseline: 3.1356x; 1.1377x over previous
//
#include <hip/hip_runtime.h>
#include <hip/hip_bf16.h>
#include <math.h>

// out[b,f,t] = sum_l sig[b,l] * win[t,l] * cos(2*pi*fv[f]*l/8192)
// R12: SINGLE dispatch, ZERO workspace. Block = one 32t x 32f x 1b output
// tile; 4 waves split K=8192 into 4 x 2048 (64 steps of 32, register-direct
// fragment generation per R10/R11: multiplicative Gaussian + stride-32
// Chebyshev cos from exact integer phase). Wave partials combined through
// 16 KB LDS (one barrier) and written straight to d_out.
// This removes the split-K partial buffer (32 MB), the reduce dispatch, and
// the inter-dispatch flush that R5-R11 all shared.
// fv/tc = linspace->int32 reproduced exactly in fp32 (R0-verified).

#define L_ 8192
#define B_ 32

typedef _Float16 half8 __attribute__((ext_vector_type(8)));
typedef __fp16 fp16x2 __attribute__((ext_vector_type(2)));
typedef float float2v __attribute__((ext_vector_type(2)));
typedef float float4v __attribute__((ext_vector_type(4)));

#define H_ 0.001220703125f                 // 1/819.2 = 5/4096 (exact)
#define CSTEP_ 7.66990393942594528198e-4f  // 2*pi/8192

__global__ __launch_bounds__(256, 2) void gabor_kernel(
    const float* __restrict__ signal, float* __restrict__ out) {
  const int bx = blockIdx.x;  // 512 = b32 * th4 * fh4
  const int b = bx & 31;
  const int th = (bx >> 5) & 3;
  const int fh = (bx >> 7) & 3;
  const int tid = threadIdx.x;
  const int lane = tid & 63;
  const int wv = tid >> 6;
  const int frow = lane & 15;
  const int quad = lane >> 4;

  __shared__ _Float16 Sg[L_];        // whole sig row, f16, 16 KB
  __shared__ float4v Acc[4][64][4];  // wave partials, 16 KB

  // ---- stage sig row b (once) ----
  {
    const float* srow = signal + (size_t)b * L_;
#pragma unroll
    for (int i = 0; i < 4; ++i) {
      const int off = i * 2048 + tid * 8;
      float4v s0 = *(const float4v*)(srow + off);
      float4v s1 = *(const float4v*)(srow + off + 4);
      union { fp16x2 h2[4]; half8 h8; } sh;
      sh.h2[0] = __builtin_amdgcn_cvt_pkrtz(s0[0], s0[1]);
      sh.h2[1] = __builtin_amdgcn_cvt_pkrtz(s0[2], s0[3]);
      sh.h2[2] = __builtin_amdgcn_cvt_pkrtz(s1[0], s1[1]);
      sh.h2[3] = __builtin_amdgcn_cvt_pkrtz(s1[2], s1[3]);
      *(half8*)&Sg[off] = sh.h8;
    }
  }
  __syncthreads();

  const int t0 = th * 32;
  const int f0 = fh * 32;
  const int k0 = wv * 2048 + quad * 8;  // this wave's first element (j=0)

  // ---- per-lane fragment state (packed f32 pairs) ----
  float2v w2[2][4], Rw2[2][4];  // Gaussian value + step-ratio
  float2v cE2[2][4], cO2[2][4]; // Chebyshev ping-pong (even/odd step)
  float2v K32v[2];
  const float2v Q32v = {0.99847528338432312012f, 0.99847528338432312012f};  // exp(-1024*H^2)
#pragma unroll
  for (int fr = 0; fr < 2; ++fr) {
    const float tc = truncf((float)(t0 + fr * 16 + frow) * (8191.0f / 127.0f));
    const int fv = (int)((float)(f0 + fr * 16 + frow) * (4096.0f / 127.0f));
    const float K32 = 2.0f * __cosf((float)((fv * 32) & (L_ - 1)) * CSTEP_);
    K32v[fr] = (float2v){K32, K32};
#pragma unroll
    for (int q = 0; q < 4; ++q) {
#pragma unroll
      for (int h = 0; h < 2; ++h) {
        const int j = 2 * q + h;
        const float x = ((float)(k0 + j) - tc) * H_;
        w2[fr][q][h] = __expf(-0.5f * x * x);
        // ratio for k += 32: exp(-32*H*x - 512*H^2)
        Rw2[fr][q][h] =
            __expf(__builtin_fmaf(-0.0390625f, x, -7.62939453125e-4f));
        cE2[fr][q][h] = __cosf((float)((fv * (k0 + j)) & (L_ - 1)) * CSTEP_);
        // value at k-32 (k0+j+8160 == k0+j-32 mod 8192)
        cO2[fr][q][h] =
            __cosf((float)((fv * (k0 + j + 8160)) & (L_ - 1)) * CSTEP_);
      }
    }
  }

  float4v acc[2][2];  // [fr1 t][fr2 f]
#pragma unroll
  for (int i = 0; i < 2; ++i)
#pragma unroll
    for (int j = 0; j < 2; ++j) acc[i][j] = (float4v)(0.0f);

  union H8 { fp16x2 h2[4]; half8 h8; };

  // ---- 64 K-steps: 32 rolled iterations x 2 ping-pong sub-steps ----
#pragma unroll 1
  for (int p = 0; p < 32; ++p) {
    // even sub-step (k = k0 + (2p)*32)
    {
      H8 ha[2], hc[2];
#pragma unroll
      for (int fr = 0; fr < 2; ++fr)
#pragma unroll
        for (int q = 0; q < 4; ++q) {
          ha[fr].h2[q] = __builtin_amdgcn_cvt_pkrtz(w2[fr][q][0], w2[fr][q][1]);
          hc[fr].h2[q] = __builtin_amdgcn_cvt_pkrtz(cE2[fr][q][0], cE2[fr][q][1]);
        }
      const half8 sgv = *(const half8*)&Sg[k0 + (2 * p) * 32];
#pragma unroll
      for (int fr2 = 0; fr2 < 2; ++fr2) {
        const half8 hbf = hc[fr2].h8 * sgv;
        acc[0][fr2] = __builtin_amdgcn_mfma_f32_16x16x32_f16(ha[0].h8, hbf,
                                                             acc[0][fr2], 0, 0, 0);
        acc[1][fr2] = __builtin_amdgcn_mfma_f32_16x16x32_f16(ha[1].h8, hbf,
                                                             acc[1][fr2], 0, 0, 0);
      }
#pragma unroll
      for (int fr = 0; fr < 2; ++fr)
#pragma unroll
        for (int q = 0; q < 4; ++q) {
          w2[fr][q] *= Rw2[fr][q];
          Rw2[fr][q] *= Q32v;
          cO2[fr][q] = __builtin_elementwise_fma(K32v[fr], cE2[fr][q], -cO2[fr][q]);
        }
    }
    // odd sub-step (k = k0 + (2p+1)*32)
    {
      H8 ha[2], hc[2];
#pragma unroll
      for (int fr = 0; fr < 2; ++fr)
#pragma unroll
        for (int q = 0; q < 4; ++q) {
          ha[fr].h2[q] = __builtin_amdgcn_cvt_pkrtz(w2[fr][q][0], w2[fr][q][1]);
          hc[fr].h2[q] = __builtin_amdgcn_cvt_pkrtz(cO2[fr][q][0], cO2[fr][q][1]);
        }
      const half8 sgv = *(const half8*)&Sg[k0 + (2 * p + 1) * 32];
#pragma unroll
      for (int fr2 = 0; fr2 < 2; ++fr2) {
        const half8 hbf = hc[fr2].h8 * sgv;
        acc[0][fr2] = __builtin_amdgcn_mfma_f32_16x16x32_f16(ha[0].h8, hbf,
                                                             acc[0][fr2], 0, 0, 0);
        acc[1][fr2] = __builtin_amdgcn_mfma_f32_16x16x32_f16(ha[1].h8, hbf,
                                                             acc[1][fr2], 0, 0, 0);
      }
#pragma unroll
      for (int fr = 0; fr < 2; ++fr)
#pragma unroll
        for (int q = 0; q < 4; ++q) {
          w2[fr][q] *= Rw2[fr][q];
          Rw2[fr][q] *= Q32v;
          cE2[fr][q] = __builtin_elementwise_fma(K32v[fr], cO2[fr][q], -cE2[fr][q]);
        }
    }
  }

  // ---- combine the 4 waves' K-partials in LDS, write d_out directly ----
#pragma unroll
  for (int i4 = 0; i4 < 4; ++i4)
    Acc[wv][lane][i4] = acc[i4 >> 1][i4 & 1];  // i4 = fr1*2 + fr2
  __syncthreads();
  // thread (wv, lane) handles i4 = wv of original lane `lane`
  float4v sum = Acc[0][lane][wv] + Acc[1][lane][wv] +
                Acc[2][lane][wv] + Acc[3][lane][wv];
  const int fr1 = wv >> 1, fr2 = wv & 1;
  const int f = f0 + fr2 * 16 + frow;
  const int t = t0 + fr1 * 16 + quad * 4;
  // D frag: col(f)=lane&15, row(t)=quad*4+reg (reg contiguous in t)
  *(float4v*)(out + ((size_t)(b * 128 + f)) * 128 + t) = sum;
}

extern "C" void kernel_launch(void* const* d_in, const int* in_sizes, int n_in,
                              void* d_out, int out_size, void* d_ws, size_t ws_size,
                              hipStream_t stream) {
  const float* signal = (const float*)d_in[0];
  float* out = (float*)d_out;
  gabor_kernel<<<dim3(512), dim3(256), 0, stream>>>(signal, out);
}